// Round 6
// baseline (487.803 us; speedup 1.0000x reference)
//
#include <hip/hip_runtime.h>
#include <hip/hip_bf16.h>

#define N_NODES 262144
#define N_GRAPHS 256
#define DMODEL 256
#define LOG2_F 0.69314718055994530942f

typedef __attribute__((ext_vector_type(4))) float f32x4;
typedef __attribute__((ext_vector_type(8))) short short8;

__device__ __forceinline__ short bf(float x) {
    __hip_bfloat16 h = __float2bfloat16(x);
    return __builtin_bit_cast(short, h);
}

// Pack g_enc (fp32 [G=256][D=256]) into bf16 B-fragments in MFMA lane order.
// chunk c = ks*16 + ntile (128 chunks of 1KB). Within chunk: lane*16B.
// B[k][g] = g_enc[g][k]; frag elem j of lane l: k = ks*32 + (l>>4)*8 + j,
// g = ntile*16 + (l&15).
__global__ void pack_b_kernel(const float* __restrict__ g_enc,
                              short* __restrict__ bout) {
    int b = blockIdx.x;        // 0..127
    int lane = threadIdx.x;    // 0..63
    int ks = b >> 4, nt = b & 15;
    int g = nt * 16 + (lane & 15);
    int k = ks * 32 + (lane >> 4) * 8;
    const float* src = g_enc + g * DMODEL + k;
    short8 v;
#pragma unroll
    for (int j = 0; j < 8; ++j) v[j] = bf(src[j]);
    reinterpret_cast<short8*>(bout)[b * 64 + lane] = v;
}

// Per wave-pass: 16 rows x 256 cols, acc[16] = 64 VGPRs.
// 8 waves -> 128 rows/pass; 8 passes -> 1024 rows/block; 256 blocks.
// __launch_bounds__(512, 1): grants the allocator up to 256-512 VGPRs.
// (512,2) and no-bounds both capped at 128 -> 200MB scratch spill (R3-R5).
// LDS (128KB) already pins occupancy at 1 block/CU, so this costs nothing.
__global__ __launch_bounds__(512, 1) void mvgrl_main(
    const float* __restrict__ l_enc, const int* __restrict__ batch,
    const short* __restrict__ bpack, double* __restrict__ partials) {
    extern __shared__ char lds_raw[];  // 128KB: full B in fragment order

    const int tid = threadIdx.x;
    const int lane = tid & 63;
    const int wave = tid >> 6;  // 0..7

    // ---- stage entire B (128KB) into LDS once ----
    {
        const short8* bp = reinterpret_cast<const short8*>(bpack);
        short8* lb = reinterpret_cast<short8*>(lds_raw);
#pragma unroll
        for (int c = 0; c < 16; ++c) {
            int chunk = wave + c * 8;
            lb[chunk * 64 + lane] = bp[chunk * 64 + lane];
        }
    }
    __syncthreads();
    // no further barriers until final reduction

    const int row_blk = blockIdx.x * 1024;
    double dSall = 0.0, dSpq = 0.0, dSpr = 0.0;

    for (int pass = 0; pass < 8; ++pass) {
        const int rowbase = row_blk + pass * 128 + wave * 16;

        f32x4 acc[16];
#pragma unroll
        for (int n = 0; n < 16; ++n) acc[n] = (f32x4){0.f, 0.f, 0.f, 0.f};

        // A fragment source: row = rowbase + (lane&15), k-base = (lane>>4)*8
        const float* arow = l_enc +
            (size_t)(rowbase + (lane & 15)) * DMODEL + (lane >> 4) * 8;

        // depth-2 prefetch of the per-ks 32B chunks
        f32x4 c0[2], c1[2];
        c0[0] = *reinterpret_cast<const f32x4*>(arow);
        c1[0] = *reinterpret_cast<const f32x4*>(arow + 4);
        c0[1] = *reinterpret_cast<const f32x4*>(arow + 32);
        c1[1] = *reinterpret_cast<const f32x4*>(arow + 36);

#pragma unroll
        for (int ks = 0; ks < 8; ++ks) {
            f32x4 f0 = c0[ks & 1], f1 = c1[ks & 1];
            if (ks < 6) {
                c0[ks & 1] = *reinterpret_cast<const f32x4*>(arow + (ks + 2) * 32);
                c1[ks & 1] = *reinterpret_cast<const f32x4*>(arow + (ks + 2) * 32 + 4);
            }
            short8 a;
            a[0] = bf(f0[0]); a[1] = bf(f0[1]); a[2] = bf(f0[2]); a[3] = bf(f0[3]);
            a[4] = bf(f1[0]); a[5] = bf(f1[1]); a[6] = bf(f1[2]); a[7] = bf(f1[3]);
#pragma unroll
            for (int nt = 0; nt < 16; ++nt) {
                short8 bfrag = *reinterpret_cast<const short8*>(
                    lds_raw + (ks * 16 + nt) * 1024 + lane * 16);
                acc[nt] = __builtin_amdgcn_mfma_f32_16x16x32_bf16(
                    a, bfrag, acc[nt], 0, 0, 0);
            }
        }

        // ---- epilogue: q = softplus(r) - log2 ----
        // C/D layout: col = nt*16 + (lane&15), row = rowbase + (lane>>4)*4 + rg
        const int rsub = (lane >> 4) * 4;
        int bvals[4];
#pragma unroll
        for (int rg = 0; rg < 4; ++rg)
            bvals[rg] = batch[rowbase + rsub + rg];

        float Sall = 0.f, Spq = 0.f, Spr = 0.f;
        const int colbase = lane & 15;
#pragma unroll
        for (int nt = 0; nt < 16; ++nt) {
            const int col = nt * 16 + colbase;
            f32x4 av = acc[nt];
#pragma unroll
            for (int rg = 0; rg < 4; ++rg) {
                float r = av[rg];
                float q = fmaxf(r, 0.f) - LOG2_F +
                          __logf(1.f + __expf(-fabsf(r)));
                Sall += q;
                if (col == bvals[rg]) { Spq += q; Spr += r; }
            }
        }
        dSall += (double)Sall;
        dSpq += (double)Spq;
        dSpr += (double)Spr;
    }

    // ---- reduction: wave shuffle -> LDS -> block partial ----
#pragma unroll
    for (int off = 32; off; off >>= 1) {
        dSall += __shfl_xor(dSall, off);
        dSpq += __shfl_xor(dSpq, off);
        dSpr += __shfl_xor(dSpr, off);
    }
    __syncthreads();  // everyone done reading B before LDS reuse
    double* red = reinterpret_cast<double*>(lds_raw);
    if (lane == 0) {
        red[wave * 3 + 0] = dSall;
        red[wave * 3 + 1] = dSpq;
        red[wave * 3 + 2] = dSpr;
    }
    __syncthreads();
    if (tid == 0) {
        double a = 0, b = 0, c = 0;
#pragma unroll
        for (int w = 0; w < 8; ++w) {
            a += red[w * 3 + 0];
            b += red[w * 3 + 1];
            c += red[w * 3 + 2];
        }
        partials[blockIdx.x * 3 + 0] = a;
        partials[blockIdx.x * 3 + 1] = b;
        partials[blockIdx.x * 3 + 2] = c;
    }
}

__global__ void finalize_kernel(const double* __restrict__ p,
                                float* __restrict__ out) {
    int t = threadIdx.x;  // 256 threads, one partial-triple each
    double a = p[t * 3 + 0], b = p[t * 3 + 1], c = p[t * 3 + 2];
#pragma unroll
    for (int off = 32; off; off >>= 1) {
        a += __shfl_xor(a, off);
        b += __shfl_xor(b, off);
        c += __shfl_xor(c, off);
    }
    __shared__ double red[12];
    int lane = t & 63, w = t >> 6;
    if (lane == 0) { red[w * 3] = a; red[w * 3 + 1] = b; red[w * 3 + 2] = c; }
    __syncthreads();
    if (t == 0) {
        double A = 0, B = 0, C = 0;
#pragma unroll
        for (int i = 0; i < 4; ++i) {
            A += red[i * 3]; B += red[i * 3 + 1]; C += red[i * 3 + 2];
        }
        // neg_sum = S_all - S_posq ; pos_sum = S_posr - S_posq
        double neg = (A - B) / ((double)N_NODES * (double)(N_GRAPHS - 1));
        double pos = (C - B) / (double)N_NODES;
        out[0] = (float)(neg - pos);
    }
}

extern "C" void kernel_launch(void* const* d_in, const int* in_sizes, int n_in,
                              void* d_out, int out_size, void* d_ws,
                              size_t ws_size, hipStream_t stream) {
    const float* l_enc = (const float*)d_in[0];
    const float* g_enc = (const float*)d_in[1];
    const int* batch = (const int*)d_in[2];
    float* out = (float*)d_out;

    short* bpack = (short*)d_ws;                           // 128KB
    double* partials = (double*)((char*)d_ws + 131072);    // 256*3 doubles

    hipFuncSetAttribute(reinterpret_cast<const void*>(mvgrl_main),
                        hipFuncAttributeMaxDynamicSharedMemorySize, 131072);

    pack_b_kernel<<<128, 64, 0, stream>>>(g_enc, bpack);
    mvgrl_main<<<256, 512, 131072, stream>>>(l_enc, batch, bpack, partials);
    finalize_kernel<<<1, 256, 0, stream>>>(partials, out);
}

// Round 7
// 122.846 us; speedup vs baseline: 3.9708x; 3.9708x over previous
//
#include <hip/hip_runtime.h>
#include <hip/hip_bf16.h>

#define N_NODES 262144
#define N_GRAPHS 256
#define DMODEL 256
#define LOG2_F 0.69314718055994530942f

typedef __attribute__((ext_vector_type(4))) float f32x4;
typedef __attribute__((ext_vector_type(8))) short short8;

__device__ __forceinline__ short bf(float x) {
    __hip_bfloat16 h = __float2bfloat16(x);
    return __builtin_bit_cast(short, h);
}

// Pack g_enc (fp32 [G=256][D=256]) into bf16 B-fragments in MFMA lane order.
// chunk c = ks*16 + ntile (128 chunks of 1KB). Within chunk: lane*16B.
// B[k][g] = g_enc[g][k]; frag elem j of lane l: k = ks*32 + (l>>4)*8 + j,
// g = ntile*16 + (l&15).
__global__ void pack_b_kernel(const float* __restrict__ g_enc,
                              short* __restrict__ bout) {
    int b = blockIdx.x;        // 0..127
    int lane = threadIdx.x;    // 0..63
    int ks = b >> 4, nt = b & 15;
    int g = nt * 16 + (lane & 15);
    int k = ks * 32 + (lane >> 4) * 8;
    const float* src = g_enc + g * DMODEL + k;
    short8 v;
#pragma unroll
    for (int j = 0; j < 8; ++j) v[j] = bf(src[j]);
    reinterpret_cast<short8*>(bout)[b * 64 + lane] = v;
}

// Per wave-pass: 16 rows x 128 cols, acc[8] = 32 VGPRs.
// Waves 0-3: col-half 0; waves 4-7: col-half 1. Pass = 64 rows; 16 passes.
// Sized so total register demand ~110 < the 128-VGPR cap rocprof showed for
// 512-thread blocks (R3-R6 all spilled ~200MB to scratch at acc[16]).
__global__ __launch_bounds__(512, 1) void mvgrl_main(
    const float* __restrict__ l_enc, const int* __restrict__ batch,
    const short* __restrict__ bpack, double* __restrict__ partials) {
    extern __shared__ char lds_raw[];  // 128KB: full B in fragment order

    const int tid = threadIdx.x;
    const int lane = tid & 63;
    const int wave = tid >> 6;   // 0..7
    const int wrow = wave & 3;   // row sub-stripe
    const int chalf = wave >> 2; // column half

    // ---- stage entire B (128KB) into LDS once ----
    {
        const short8* bp = reinterpret_cast<const short8*>(bpack);
        short8* lb = reinterpret_cast<short8*>(lds_raw);
#pragma unroll
        for (int c = 0; c < 16; ++c) {
            int chunk = wave + c * 8;
            lb[chunk * 64 + lane] = bp[chunk * 64 + lane];
        }
    }
    __syncthreads();
    // no further barriers until final reduction

    const int row_blk = blockIdx.x * 1024;
    double dSall = 0.0, dSpq = 0.0, dSpr = 0.0;

    for (int pass = 0; pass < 16; ++pass) {
        const int rowbase = row_blk + pass * 64 + wrow * 16;

        f32x4 acc[8];
#pragma unroll
        for (int n = 0; n < 8; ++n) acc[n] = (f32x4){0.f, 0.f, 0.f, 0.f};

        // A fragment source: row = rowbase + (lane&15), k-base = (lane>>4)*8
        const float* arow = l_enc +
            (size_t)(rowbase + (lane & 15)) * DMODEL + (lane >> 4) * 8;

        // depth-1 prefetch: keep next ks chunk in flight under the MFMAs
        f32x4 pa0 = *reinterpret_cast<const f32x4*>(arow);
        f32x4 pa1 = *reinterpret_cast<const f32x4*>(arow + 4);

#pragma unroll 1
        for (int ks = 0; ks < 8; ++ks) {
            f32x4 f0 = pa0, f1 = pa1;
            if (ks < 7) {
                pa0 = *reinterpret_cast<const f32x4*>(arow + (ks + 1) * 32);
                pa1 = *reinterpret_cast<const f32x4*>(arow + (ks + 1) * 32 + 4);
            }
            short8 a;
            a[0] = bf(f0[0]); a[1] = bf(f0[1]); a[2] = bf(f0[2]); a[3] = bf(f0[3]);
            a[4] = bf(f1[0]); a[5] = bf(f1[1]); a[6] = bf(f1[2]); a[7] = bf(f1[3]);
            const char* bbase = lds_raw + (ks * 16 + chalf * 8) * 1024 + lane * 16;
#pragma unroll
            for (int nt = 0; nt < 8; ++nt) {
                short8 bfrag = *reinterpret_cast<const short8*>(bbase + nt * 1024);
                acc[nt] = __builtin_amdgcn_mfma_f32_16x16x32_bf16(
                    a, bfrag, acc[nt], 0, 0, 0);
            }
        }

        // ---- epilogue: q = softplus(r) - log2 ----
        // C/D layout: col = (chalf*8+nt)*16 + (lane&15),
        //             row = rowbase + (lane>>4)*4 + rg
        const int rsub = (lane >> 4) * 4;
        int bvals[4];
#pragma unroll
        for (int rg = 0; rg < 4; ++rg)
            bvals[rg] = batch[rowbase + rsub + rg];

        float Sall = 0.f, Spq = 0.f, Spr = 0.f;
        const int colbase = chalf * 128 + (lane & 15);
#pragma unroll
        for (int nt = 0; nt < 8; ++nt) {
            const int col = colbase + nt * 16;
            f32x4 av = acc[nt];
#pragma unroll
            for (int rg = 0; rg < 4; ++rg) {
                float r = av[rg];
                float q = fmaxf(r, 0.f) - LOG2_F +
                          __logf(1.f + __expf(-fabsf(r)));
                Sall += q;
                if (col == bvals[rg]) { Spq += q; Spr += r; }
            }
        }
        dSall += (double)Sall;
        dSpq += (double)Spq;
        dSpr += (double)Spr;
    }

    // ---- reduction: wave shuffle -> LDS -> block partial ----
#pragma unroll
    for (int off = 32; off; off >>= 1) {
        dSall += __shfl_xor(dSall, off);
        dSpq += __shfl_xor(dSpq, off);
        dSpr += __shfl_xor(dSpr, off);
    }
    __syncthreads();  // everyone done reading B before LDS reuse
    double* red = reinterpret_cast<double*>(lds_raw);
    if (lane == 0) {
        red[wave * 3 + 0] = dSall;
        red[wave * 3 + 1] = dSpq;
        red[wave * 3 + 2] = dSpr;
    }
    __syncthreads();
    if (tid == 0) {
        double a = 0, b = 0, c = 0;
#pragma unroll
        for (int w = 0; w < 8; ++w) {
            a += red[w * 3 + 0];
            b += red[w * 3 + 1];
            c += red[w * 3 + 2];
        }
        partials[blockIdx.x * 3 + 0] = a;
        partials[blockIdx.x * 3 + 1] = b;
        partials[blockIdx.x * 3 + 2] = c;
    }
}

__global__ void finalize_kernel(const double* __restrict__ p,
                                float* __restrict__ out) {
    int t = threadIdx.x;  // 256 threads, one partial-triple each
    double a = p[t * 3 + 0], b = p[t * 3 + 1], c = p[t * 3 + 2];
#pragma unroll
    for (int off = 32; off; off >>= 1) {
        a += __shfl_xor(a, off);
        b += __shfl_xor(b, off);
        c += __shfl_xor(c, off);
    }
    __shared__ double red[12];
    int lane = t & 63, w = t >> 6;
    if (lane == 0) { red[w * 3] = a; red[w * 3 + 1] = b; red[w * 3 + 2] = c; }
    __syncthreads();
    if (t == 0) {
        double A = 0, B = 0, C = 0;
#pragma unroll
        for (int i = 0; i < 4; ++i) {
            A += red[i * 3]; B += red[i * 3 + 1]; C += red[i * 3 + 2];
        }
        // neg_sum = S_all - S_posq ; pos_sum = S_posr - S_posq
        double neg = (A - B) / ((double)N_NODES * (double)(N_GRAPHS - 1));
        double pos = (C - B) / (double)N_NODES;
        out[0] = (float)(neg - pos);
    }
}

extern "C" void kernel_launch(void* const* d_in, const int* in_sizes, int n_in,
                              void* d_out, int out_size, void* d_ws,
                              size_t ws_size, hipStream_t stream) {
    const float* l_enc = (const float*)d_in[0];
    const float* g_enc = (const float*)d_in[1];
    const int* batch = (const int*)d_in[2];
    float* out = (float*)d_out;

    short* bpack = (short*)d_ws;                           // 128KB
    double* partials = (double*)((char*)d_ws + 131072);    // 256*3 doubles

    hipFuncSetAttribute(reinterpret_cast<const void*>(mvgrl_main),
                        hipFuncAttributeMaxDynamicSharedMemorySize, 131072);

    pack_b_kernel<<<128, 64, 0, stream>>>(g_enc, bpack);
    mvgrl_main<<<256, 512, 131072, stream>>>(l_enc, batch, bpack, partials);
    finalize_kernel<<<1, 256, 0, stream>>>(partials, out);
}